// Round 12
// baseline (183.770 us; speedup 1.0000x reference)
//
#include <hip/hip_runtime.h>

// ConvNat: 2x NAT(31x31, 4 heads, dh=16) on 36x36x64 + dw-conv3x3 residual + linear.
// fp32. R12: 5 launches. combine1+qkv2 fused (proj recomputed per row-group in
// LDS; planar writes stay coalesced; natA round-trip eliminated). qkv_w2
// transposed alongside proj/lin weights in the layer-1 qkv launch.

namespace {

__device__ __forceinline__ int iclampi(int v, int lo, int hi) {
  return v < lo ? lo : (v > hi ? hi : v);
}

// Fused qkv GEMM (planar out) + (layer 1 only) weight transposes.
// qkv blocks [0,1008): pg = bid%21 (64-pixel group), rg = bid/21 (4 rows of 192).
// x tile in LDS [64][65]; wave = one row x 64 pixels; coalesced planar writes.
// WITH_T blocks [1008,1056): transpose proj_w1/proj_w2/lin_w (64x64 each).
// WITH_T blocks [1056,1104): transpose qkv_w2 (192x64) -> w2T[cc*192+r].
template <bool WITH_T>
__global__ __launch_bounds__(256) void qkv_fused(
    const float* __restrict__ xin, const float* __restrict__ w,
    const float* __restrict__ b, float* __restrict__ planes,
    const float* __restrict__ pw1, const float* __restrict__ pw2,
    const float* __restrict__ lw, const float* __restrict__ w2,
    float* __restrict__ wT) {
  const int bid = blockIdx.x;
  const int tid = threadIdx.x;
  if (WITH_T && bid >= 1008) {
    const int t = bid - 1008;  // 0..95
    if (t < 48) {              // three 64x64 transposes
      const int m = t >> 4;
      const int idx = (t & 15) * 256 + tid;
      const float* src = m == 0 ? pw1 : (m == 1 ? pw2 : lw);
      wT[m * 4096 + (idx & 63) * 64 + (idx >> 6)] = src[idx];
    } else {                   // qkv_w2: 192x64 -> w2T[cc*192 + r]
      const int idx = (t - 48) * 256 + tid;  // 0..12287
      const int r = idx >> 6, cc = idx & 63;
      wT[12288 + cc * 192 + r] = w2[idx];
    }
    return;
  }
  __shared__ float xs[64][65];
  __shared__ float ws4[4][64];
  const int pg = bid % 21, rg = bid / 21;
  const int wv = tid >> 6, lane = tid & 63;
  const int n0 = pg * 64;
  const int base = n0 * 64;
  const int maxf = 82944 - base;
  const float* xb = xin + base;
#pragma unroll
  for (int t4 = 0; t4 < 4; ++t4) {
    const int fi = (tid + t4 * 256) * 4;
    float4 v = make_float4(0.f, 0.f, 0.f, 0.f);
    if (fi < maxf) v = *(const float4*)(xb + fi);
    const int p = fi >> 6, c = fi & 63;
    xs[p][c] = v.x; xs[p][c + 1] = v.y; xs[p][c + 2] = v.z; xs[p][c + 3] = v.w;
  }
  ws4[tid >> 6][tid & 63] = w[rg * 256 + tid];
  __syncthreads();
  const int r = rg * 4 + wv;
  float acc = b[r];
#pragma unroll
  for (int cc = 0; cc < 64; ++cc) acc += xs[lane][cc] * ws4[wv][cc];
  const int n = n0 + lane;
  if (n < 1296) planes[r * 1296 + n] = acc;
}

// Split-K NAT partials on planar K/V. grid = 324*4*2; wave = head. (unchanged)
__global__ __launch_bounds__(256, 2) void nat_attn_part(
    const float* __restrict__ planes, const float* __restrict__ rpb,
    float* __restrict__ part) {
  __shared__ float lpart[4][16][35];

  const int tid = threadIdx.x;
  const int h = tid >> 6;
  const int lane = tid & 63;
  const int bid = blockIdx.x;
  const int tile = bid >> 3;
  const int s = (bid >> 1) & 3;
  const int pr = bid & 1;
  const int i0 = (tile / 18) * 2;
  const int j0 = (tile % 18) * 2;

  const int r_lo = iclampi(i0 - 15, 0, 5);
  const int nRr = (iclampi(i0 - 14, 0, 5) + 30) - r_lo;
  const int c_lo = iclampi(j0 - 15, 0, 5);
  const int nCc = (iclampi(j0 - 14, 0, 5) + 30) - c_lo;

  const int iq = i0 + pr;
  const int riq = iclampi(iq - 15, 0, 5);
  int jq[2], cjq[2];
#pragma unroll
  for (int qq = 0; qq < 2; ++qq) {
    jq[qq] = j0 + qq;
    cjq[qq] = iclampi(jq[qq] - 15, 0, 5);
  }

  const float* Qp = planes + (size_t)(h * 16) * 1296;
  const float* Kp = planes + (size_t)(64 + h * 16) * 1296;
  const float* Vp = planes + (size_t)(128 + h * 16) * 1296;

  float qv[2][16];
#pragma unroll
  for (int qq = 0; qq < 2; ++qq) {
    const int nq = iq * 36 + jq[qq];
#pragma unroll
    for (int d = 0; d < 16; ++d) qv[qq][d] = Qp[d * 1296 + nq] * 0.25f;
  }

  float acc[2][16];
  float sden[2] = {0.f, 0.f};
#pragma unroll
  for (int qq = 0; qq < 2; ++qq)
#pragma unroll
    for (int d = 0; d < 16; ++d) acc[qq][d] = 0.f;

  const int lr = lane >> 5;
  const int lc = lane & 31;

#pragma unroll
  for (int rp = 0; rp < 4; ++rp) {
    const int krr = s * 8 + rp * 2 + lr;
    const int rA = r_lo + krr;
    const int cA = c_lo + lc;
    const bool act = (krr <= nRr) && (lc <= nCc);
    const int rL = rA > 35 ? 35 : rA;
    const int cL = cA > 35 ? 35 : cA;
    const int nk = rL * 36 + cL;
    float kr_[16], vr_[16];
#pragma unroll
    for (int d = 0; d < 16; ++d) kr_[d] = Kp[d * 1296 + nk];
#pragma unroll
    for (int d = 0; d < 16; ++d) vr_[d] = Vp[d * 1296 + nk];

    float dot[2] = {0.f, 0.f};
#pragma unroll
    for (int d = 0; d < 16; ++d) {
      dot[0] += qv[0][d] * kr_[d];
      dot[1] += qv[1][d] * kr_[d];
    }
    const bool rowok = act && (rA >= riq) && (rA <= riq + 30);
    const int br = iclampi(rA - iq + 30, 0, 60);
#pragma unroll
    for (int qq = 0; qq < 2; ++qq) {
      const bool inw = rowok && (cA >= cjq[qq]) && (cA <= cjq[qq] + 30);
      const int bc = iclampi(cA - jq[qq] + 30, 0, 60);
      const float bias = rpb[h * 3721 + br * 61 + bc];
      const float lg = fminf(dot[qq] + bias, 25.f);
      const float p = inw ? __expf(lg) : 0.f;
      sden[qq] += p;
#pragma unroll
      for (int d = 0; d < 16; ++d) acc[qq][d] += p * vr_[d];
    }
  }

#pragma unroll
  for (int qq = 0; qq < 2; ++qq) {
#pragma unroll
    for (int d = 0; d < 16; ++d) {
      acc[qq][d] += __shfl_xor(acc[qq][d], 1);
      acc[qq][d] += __shfl_xor(acc[qq][d], 2);
    }
    sden[qq] += __shfl_xor(sden[qq], 1);
    sden[qq] += __shfl_xor(sden[qq], 2);
  }

  if ((lane & 3) == 0) {
    const int row = lane >> 2;
#pragma unroll
    for (int qq = 0; qq < 2; ++qq) {
#pragma unroll
      for (int d = 0; d < 16; ++d) lpart[h][row][qq * 17 + d] = acc[qq][d];
      lpart[h][row][qq * 17 + 16] = sden[qq];
    }
  }
  // wave-private LDS slab: same wave writes+reads.

  float* wsout = part + ((size_t)bid * 4 + h) * 36;
  if (lane < 34) {
    float t0 = 0.f;
#pragma unroll
    for (int l = 0; l < 16; ++l) t0 += lpart[h][l][lane];
    wsout[lane] = t0;
  }
}

// Fused: softmax-normalize layer-1 partials -> proj (natA, LDS only) -> layer-2
// qkv rows -> planes. grid = 21 pixel-groups x 24 row-groups = 504, block 256.
// Proj recomputed per row-group (cheap); planar writes coalesced over pixels.
__global__ __launch_bounds__(256) void combine_qkv2(
    const float* __restrict__ part, const float* __restrict__ pwT1,
    const float* __restrict__ pb1, const float* __restrict__ w2T,
    const float* __restrict__ b2, float* __restrict__ planes) {
  __shared__ float att[64][65];  // (p+cc)%32 banking -> <=2-way, free
  __shared__ float nat[64][65];
  const int tid = threadIdx.x;
  const int pg = blockIdx.x % 21, rg = blockIdx.x / 21;
  const int n0 = pg * 64;
  const int p = tid & 63, hh = tid >> 6;

  // phase A: att[p][hh*16+dd] from layer-1 partials
  {
    int n = n0 + p;
    if (n > 1295) n = 1295;
    const int iq = n / 36, jq = n % 36;
    const int tile = (iq >> 1) * 18 + (jq >> 1);
    const int pr = iq & 1, qq = jq & 1;
    const float* pb_ = part + ((size_t)(tile * 8 + pr) * 4 + hh) * 36 + qq * 17;
    float num[16];
    float den = 0.f;
#pragma unroll
    for (int dd = 0; dd < 16; ++dd) num[dd] = 0.f;
#pragma unroll
    for (int sp = 0; sp < 4; ++sp) {
      const float* rec = pb_ + sp * 288;
      den += rec[16];
#pragma unroll
      for (int dd = 0; dd < 16; ++dd) num[dd] += rec[dd];
    }
    const float inv = 1.f / den;
#pragma unroll
    for (int dd = 0; dd < 16; ++dd) att[p][hh * 16 + dd] = num[dd] * inv;
  }
  __syncthreads();

  // phase B: nat[p][c] = pb1[c] + sum_cc att[p][cc]*pwT1[cc*64+c], c=hh*16+k
  {
    float acc[16];
#pragma unroll
    for (int k = 0; k < 16; ++k) acc[k] = pb1[hh * 16 + k];
    for (int cc = 0; cc < 64; ++cc) {
      const float a = att[p][cc];
      const float* wp = pwT1 + cc * 64 + hh * 16;  // wave-uniform -> scalar loads
#pragma unroll
      for (int k = 0; k < 16; ++k) acc[k] += a * wp[k];
    }
#pragma unroll
    for (int k = 0; k < 16; ++k) nat[p][hh * 16 + k] = acc[k];
  }
  __syncthreads();

  // phase C: rows r0,r1 = rg*8 + hh*2 + {0,1}; pixel = p; coalesced write
  {
    const int n = n0 + p;
    const int r0 = rg * 8 + hh * 2, r1 = r0 + 1;
    float a0 = b2[r0], a1 = b2[r1];
    for (int cc = 0; cc < 64; ++cc) {
      const float a = nat[p][cc];
      a0 += a * w2T[cc * 192 + r0];  // wave-uniform -> scalar
      a1 += a * w2T[cc * 192 + r1];
    }
    if (n < 1296) {
      planes[r0 * 1296 + n] = a0;
      planes[r1 * 1296 + n] = a1;
    }
  }
}

// Layer-2 combine + dwconv residual + final linear. grid=324, block=256. (as R11)
__global__ __launch_bounds__(256) void combine_final(
    const float* __restrict__ part, const float* __restrict__ pwT,
    const float* __restrict__ pb, const float* __restrict__ x,
    const float* __restrict__ dww, const float* __restrict__ dwb,
    const float* __restrict__ linT, const float* __restrict__ lb,
    float* __restrict__ out) {
  __shared__ float att[4][64];
  __shared__ float y_lds[4][64];
  const int tid = threadIdx.x;
  const int q = tid >> 6, lane = tid & 63;
  const int tile = blockIdx.x;
  const int i0 = (tile / 18) * 2, j0 = (tile % 18) * 2;
  const int p = q >> 1, qq = q & 1;
  const int iq = i0 + p, jq = j0 + qq;
  const int n = iq * 36 + jq;

  const int hh = lane >> 4, dd = lane & 15;
  const float* pbase = part + ((size_t)tile * 8 + p) * 144 + hh * 36 + qq * 17;
  float num = 0.f, den = 0.f;
#pragma unroll
  for (int sp = 0; sp < 4; ++sp) {
    num += pbase[sp * 288 + dd];
    den += pbase[sp * 288 + 16];
  }
  att[q][lane] = num / den;
  __syncthreads();

  float a = pb[lane];
#pragma unroll
  for (int cc = 0; cc < 64; ++cc) a += att[q][cc] * pwT[cc * 64 + lane];

  float y = a + dwb[lane];
#pragma unroll
  for (int di = -1; di <= 1; ++di) {
#pragma unroll
    for (int dj = -1; dj <= 1; ++dj) {
      const int ii = iq + di, jj = jq + dj;
      if (ii >= 0 && ii < 36 && jj >= 0 && jj < 36)
        y += x[(ii * 36 + jj) * 64 + lane] * dww[lane * 9 + (di + 1) * 3 + (dj + 1)];
    }
  }
  y_lds[q][lane] = y;
  __syncthreads();
  float o = lb[lane];
#pragma unroll
  for (int cc = 0; cc < 64; ++cc) o += y_lds[q][cc] * linT[cc * 64 + lane];
  out[n * 64 + lane] = o;
}

}  // namespace

extern "C" void kernel_launch(void* const* d_in, const int* in_sizes, int n_in,
                              void* d_out, int out_size, void* d_ws, size_t ws_size,
                              hipStream_t stream) {
  const float* x       = (const float*)d_in[0];
  const float* qkv_w1  = (const float*)d_in[3];
  const float* qkv_b1  = (const float*)d_in[4];
  const float* rpb1    = (const float*)d_in[5];
  const float* proj_w1 = (const float*)d_in[6];
  const float* proj_b1 = (const float*)d_in[7];
  const float* qkv_w2  = (const float*)d_in[8];
  const float* qkv_b2  = (const float*)d_in[9];
  const float* rpb2    = (const float*)d_in[10];
  const float* proj_w2 = (const float*)d_in[11];
  const float* proj_b2 = (const float*)d_in[12];
  const float* dw_w    = (const float*)d_in[13];
  const float* dw_b    = (const float*)d_in[14];
  const float* lin_w   = (const float*)d_in[15];
  const float* lin_b   = (const float*)d_in[16];
  float* out = (float*)d_out;

  float* ws = (float*)d_ws;
  float* planes = ws;              // 192*1296  = 248832 floats
  float* partb  = ws + 248832;     // 2592*4*36 = 373248 floats
  float* wT     = partb + 373248;  // 3*4096 + 192*64 = 24576 floats
  float* pwT1 = wT;
  float* pwT2 = wT + 4096;
  float* linT = wT + 8192;
  float* w2T  = wT + 12288;

  // layer 1 (qkv + all weight transposes in one launch)
  qkv_fused<true><<<1104, 256, 0, stream>>>(x, qkv_w1, qkv_b1, planes,
                                            proj_w1, proj_w2, lin_w, qkv_w2, wT);
  nat_attn_part<<<2592, 256, 0, stream>>>(planes, rpb1, partb);
  // combine layer-1 + qkv layer-2 fused (natA never hits memory)
  combine_qkv2<<<504, 256, 0, stream>>>(partb, pwT1, proj_b1, w2T, qkv_b2,
                                        planes);
  nat_attn_part<<<2592, 256, 0, stream>>>(planes, rpb2, partb);
  // layer-2 combine + dwconv residual + final linear
  combine_final<<<324, 256, 0, stream>>>(partb, pwT2, proj_b2, x,
                                         dw_w, dw_b, linT, lin_b, out);
}

// Round 13
// 177.136 us; speedup vs baseline: 1.0374x; 1.0374x over previous
//
#include <hip/hip_runtime.h>

// ConvNat: 2x NAT(31x31, 4 heads, dh=16) on 36x36x64 + dw-conv3x3 residual + linear.
// fp32. R13: R11 structure (6 launches, best measured 166.6us), with attention
// reverted to 4-queries-per-lane (no pr split): halves K/V global traffic
// (340->170 MB/dispatch) and doubles FMA-per-load ILP. grid = 324 tiles x 4
// key-splits. Partial records = R1's 72-float layout.

namespace {

__device__ __forceinline__ int iclampi(int v, int lo, int hi) {
  return v < lo ? lo : (v > hi ? hi : v);
}

// Fused qkv GEMM (planar out) + (layer 1 only) proj/lin weight transposes.
// qkv blocks [0,1008): pg = bid%21 (64-pixel group), rg = bid/21 (4 rows of 192).
// x tile in LDS [64][65]; wave = one row x 64 pixels; coalesced planar writes.
// WITH_T blocks [1008,1056): transpose proj_w1/proj_w2/lin_w (64x64 each).
template <bool WITH_T>
__global__ __launch_bounds__(256) void qkv_fused(
    const float* __restrict__ xin, const float* __restrict__ w,
    const float* __restrict__ b, float* __restrict__ planes,
    const float* __restrict__ pw1, const float* __restrict__ pw2,
    const float* __restrict__ lw, float* __restrict__ wT) {
  const int bid = blockIdx.x;
  const int tid = threadIdx.x;
  if (WITH_T && bid >= 1008) {
    const int t = bid - 1008;  // 0..47, 16 blocks per 64x64 matrix
    const int m = t >> 4;
    const int idx = (t & 15) * 256 + tid;
    const float* src = m == 0 ? pw1 : (m == 1 ? pw2 : lw);
    wT[m * 4096 + (idx & 63) * 64 + (idx >> 6)] = src[idx];
    return;
  }
  __shared__ float xs[64][65];
  __shared__ float ws4[4][64];
  const int pg = bid % 21, rg = bid / 21;
  const int wv = tid >> 6, lane = tid & 63;
  const int n0 = pg * 64;
  const int base = n0 * 64;
  const int maxf = 82944 - base;
  const float* xb = xin + base;
#pragma unroll
  for (int t4 = 0; t4 < 4; ++t4) {
    const int fi = (tid + t4 * 256) * 4;
    float4 v = make_float4(0.f, 0.f, 0.f, 0.f);
    if (fi < maxf) v = *(const float4*)(xb + fi);
    const int p = fi >> 6, c = fi & 63;
    xs[p][c] = v.x; xs[p][c + 1] = v.y; xs[p][c + 2] = v.z; xs[p][c + 3] = v.w;
  }
  ws4[tid >> 6][tid & 63] = w[rg * 256 + tid];
  __syncthreads();
  const int r = rg * 4 + wv;
  float acc = b[r];
#pragma unroll
  for (int cc = 0; cc < 64; ++cc) acc += xs[lane][cc] * ws4[wv][cc];
  const int n = n0 + lane;
  if (n < 1296) planes[r * 1296 + n] = acc;
}

// Split-K NAT partials on planar K/V, 4 queries per lane (full 2x2 tile).
// grid = 324 tiles * 4 splits: tile = bid>>2, s = bid&3. Wave = head.
// Split s covers key rows [s*8, s*8+8) of the <=32-row window union: 4 rp of
// 2 rows x 32 cols. Record per (bid, head): 72 floats, [q*17+d], [q*17+16]=den.
__global__ __launch_bounds__(256, 2) void nat_attn_part(
    const float* __restrict__ planes, const float* __restrict__ rpb,
    float* __restrict__ part) {
  __shared__ float lpart[4][16][69];  // [head][group][4q*17] stride 69

  const int tid = threadIdx.x;
  const int h = tid >> 6;
  const int lane = tid & 63;
  const int bid = blockIdx.x;
  const int tile = bid >> 2;
  const int s = bid & 3;
  const int i0 = (tile / 18) * 2;
  const int j0 = (tile % 18) * 2;

  const int r_lo = iclampi(i0 - 15, 0, 5);
  const int nRr = (iclampi(i0 - 14, 0, 5) + 30) - r_lo;  // 30 or 31
  const int c_lo = iclampi(j0 - 15, 0, 5);
  const int nCc = (iclampi(j0 - 14, 0, 5) + 30) - c_lo;

  int iq[4], jq[4], riq[4], cjq[4];
#pragma unroll
  for (int qq = 0; qq < 4; ++qq) {
    iq[qq] = i0 + (qq >> 1);
    jq[qq] = j0 + (qq & 1);
    riq[qq] = iclampi(iq[qq] - 15, 0, 5);
    cjq[qq] = iclampi(jq[qq] - 15, 0, 5);
  }

  const float* Qp = planes + (size_t)(h * 16) * 1296;
  const float* Kp = planes + (size_t)(64 + h * 16) * 1296;
  const float* Vp = planes + (size_t)(128 + h * 16) * 1296;

  // queries (broadcast loads), pre-scaled by dh^-0.5 = 0.25
  float qv[4][16];
#pragma unroll
  for (int qq = 0; qq < 4; ++qq) {
    const int nq = iq[qq] * 36 + jq[qq];
#pragma unroll
    for (int d = 0; d < 16; ++d) qv[qq][d] = Qp[d * 1296 + nq] * 0.25f;
  }

  float acc[4][16];
  float sden[4] = {0.f, 0.f, 0.f, 0.f};
#pragma unroll
  for (int qq = 0; qq < 4; ++qq)
#pragma unroll
    for (int d = 0; d < 16; ++d) acc[qq][d] = 0.f;

  const int lr = lane >> 5;
  const int lc = lane & 31;

#pragma unroll
  for (int rp = 0; rp < 4; ++rp) {
    const int krr = s * 8 + rp * 2 + lr;
    const int rA = r_lo + krr;
    const int cA = c_lo + lc;
    const bool act = (krr <= nRr) && (lc <= nCc);
    const int rL = rA > 35 ? 35 : rA;
    const int cL = cA > 35 ? 35 : cA;
    const int nk = rL * 36 + cL;
    float kr_[16], vr_[16];
#pragma unroll
    for (int d = 0; d < 16; ++d) kr_[d] = Kp[d * 1296 + nk];
#pragma unroll
    for (int d = 0; d < 16; ++d) vr_[d] = Vp[d * 1296 + nk];

#pragma unroll
    for (int qq = 0; qq < 4; ++qq) {
      float dot = 0.f;
#pragma unroll
      for (int d = 0; d < 16; ++d) dot += qv[qq][d] * kr_[d];
      const bool inw = act && (rA >= riq[qq]) && (rA <= riq[qq] + 30) &&
                       (cA >= cjq[qq]) && (cA <= cjq[qq] + 30);
      const int br = iclampi(rA - iq[qq] + 30, 0, 60);
      const int bc = iclampi(cA - jq[qq] + 30, 0, 60);
      const float bias = rpb[h * 3721 + br * 61 + bc];
      const float lg = fminf(dot + bias, 25.f);  // overflow insurance
      const float p = inw ? __expf(lg) : 0.f;
      sden[qq] += p;
#pragma unroll
      for (int d = 0; d < 16; ++d) acc[qq][d] += p * vr_[d];
    }
  }

  // 2-step butterfly -> 16 groups of 4 lanes
#pragma unroll
  for (int qq = 0; qq < 4; ++qq) {
#pragma unroll
    for (int d = 0; d < 16; ++d) {
      acc[qq][d] += __shfl_xor(acc[qq][d], 1);
      acc[qq][d] += __shfl_xor(acc[qq][d], 2);
    }
    sden[qq] += __shfl_xor(sden[qq], 1);
    sden[qq] += __shfl_xor(sden[qq], 2);
  }

  if ((lane & 3) == 0) {
    const int row = lane >> 2;
#pragma unroll
    for (int qq = 0; qq < 4; ++qq) {
#pragma unroll
      for (int d = 0; d < 16; ++d) lpart[h][row][qq * 17 + d] = acc[qq][d];
      lpart[h][row][qq * 17 + 16] = sden[qq];
    }
  }
  // wave-private LDS slab: same wave writes+reads, no __syncthreads needed.

  float* wsout = part + ((size_t)bid * 4 + h) * 72;
  {
    float t0 = 0.f;
#pragma unroll
    for (int l = 0; l < 16; ++l) t0 += lpart[h][l][lane];
    wsout[lane] = t0;
    if (lane < 4) {
      float t1 = 0.f;
#pragma unroll
      for (int l = 0; l < 16; ++l) t1 += lpart[h][l][lane + 64];
      wsout[lane + 64] = t1;
    }
  }
}

// Combine partials -> normalize -> projection (transposed weights, coalesced).
// FINAL adds dwconv residual + final linear. grid = 324, block = 256 (wave=query).
// Record layout: part[tile*1152 + sp*288 + hh*72 + q*17 + {dd|16}].
template <bool FINAL>
__global__ __launch_bounds__(256) void nat_combine(
    const float* __restrict__ part, const float* __restrict__ pwT,
    const float* __restrict__ pb, const float* __restrict__ x,
    const float* __restrict__ dww, const float* __restrict__ dwb,
    const float* __restrict__ linT, const float* __restrict__ lb,
    float* __restrict__ out) {
  __shared__ float att[4][64];
  __shared__ float y_lds[4][64];
  const int tid = threadIdx.x;
  const int q = tid >> 6, lane = tid & 63;
  const int tile = blockIdx.x;
  const int i0 = (tile / 18) * 2, j0 = (tile % 18) * 2;
  const int iq = i0 + (q >> 1), jq = j0 + (q & 1);
  const int n = iq * 36 + jq;

  const int hh = lane >> 4, dd = lane & 15;
  const float* pbase = part + (size_t)tile * 1152 + hh * 72 + q * 17;
  float num = 0.f, den = 0.f;
#pragma unroll
  for (int sp = 0; sp < 4; ++sp) {
    num += pbase[sp * 288 + dd];
    den += pbase[sp * 288 + 16];
  }
  att[q][lane] = num / den;
  __syncthreads();

  float a = pb[lane];
#pragma unroll
  for (int cc = 0; cc < 64; ++cc) a += att[q][cc] * pwT[cc * 64 + lane];

  if (!FINAL) {
    out[n * 64 + lane] = a;
  } else {
    float y = a + dwb[lane];
#pragma unroll
    for (int di = -1; di <= 1; ++di) {
#pragma unroll
      for (int dj = -1; dj <= 1; ++dj) {
        const int ii = iq + di, jj = jq + dj;
        if (ii >= 0 && ii < 36 && jj >= 0 && jj < 36)
          y += x[(ii * 36 + jj) * 64 + lane] * dww[lane * 9 + (di + 1) * 3 + (dj + 1)];
      }
    }
    y_lds[q][lane] = y;
    __syncthreads();
    float o = lb[lane];
#pragma unroll
    for (int cc = 0; cc < 64; ++cc) o += y_lds[q][cc] * linT[cc * 64 + lane];
    out[n * 64 + lane] = o;
  }
}

}  // namespace

extern "C" void kernel_launch(void* const* d_in, const int* in_sizes, int n_in,
                              void* d_out, int out_size, void* d_ws, size_t ws_size,
                              hipStream_t stream) {
  const float* x       = (const float*)d_in[0];
  const float* qkv_w1  = (const float*)d_in[3];
  const float* qkv_b1  = (const float*)d_in[4];
  const float* rpb1    = (const float*)d_in[5];
  const float* proj_w1 = (const float*)d_in[6];
  const float* proj_b1 = (const float*)d_in[7];
  const float* qkv_w2  = (const float*)d_in[8];
  const float* qkv_b2  = (const float*)d_in[9];
  const float* rpb2    = (const float*)d_in[10];
  const float* proj_w2 = (const float*)d_in[11];
  const float* proj_b2 = (const float*)d_in[12];
  const float* dw_w    = (const float*)d_in[13];
  const float* dw_b    = (const float*)d_in[14];
  const float* lin_w   = (const float*)d_in[15];
  const float* lin_b   = (const float*)d_in[16];
  float* out = (float*)d_out;

  float* ws = (float*)d_ws;
  float* planes = ws;              // 192*1296  = 248832 floats
  float* natA   = ws + 248832;     // 1296*64   =  82944 floats
  float* partb  = natA + 82944;    // 1296*4*72 = 373248 floats
  float* wT     = partb + 373248;  // 3*4096    =  12288 floats
  float* pwT1 = wT;
  float* pwT2 = wT + 4096;
  float* linT = wT + 8192;

  // layer 1 (qkv + weight transposes fused into one launch)
  qkv_fused<true><<<1056, 256, 0, stream>>>(x, qkv_w1, qkv_b1, planes,
                                            proj_w1, proj_w2, lin_w, wT);
  nat_attn_part<<<1296, 256, 0, stream>>>(planes, rpb1, partb);
  nat_combine<false><<<324, 256, 0, stream>>>(partb, pwT1, proj_b1, nullptr,
                                              nullptr, nullptr, nullptr, nullptr,
                                              natA);
  // layer 2
  qkv_fused<false><<<1008, 256, 0, stream>>>(natA, qkv_w2, qkv_b2, planes,
                                             nullptr, nullptr, nullptr, nullptr);
  nat_attn_part<<<1296, 256, 0, stream>>>(planes, rpb2, partb);
  // layer-2 combine + dwconv residual + final linear
  nat_combine<true><<<324, 256, 0, stream>>>(partb, pwT2, proj_b2, x,
                                             dw_w, dw_b, linT, lin_b, out);
}

// Round 14
// 149.464 us; speedup vs baseline: 1.2295x; 1.1851x over previous
//
#include <hip/hip_runtime.h>

// ConvNat: 2x NAT(31x31, 4 heads, dh=16) on 36x36x64 + dw-conv3x3 residual + linear.
// fp32. R14: R11 structure; attention rewritten for vectorized K/V:
// planar rows are contiguous+aligned -> scan full 36-col rows as float4.
// lane = (row 0..6, colgroup 0..8); 4 keys per lane per load -> 4x fewer load
// instructions (R13 showed we're latency/issue-bound, not traffic-bound).
// grid = 324 tiles x 5 row-splits x 2 query-rows; one row-iteration per block.
// Q staged in wave-private LDS (keeps VGPR ~90, avoids R13's spill at 128).

namespace {

__device__ __forceinline__ int iclampi(int v, int lo, int hi) {
  return v < lo ? lo : (v > hi ? hi : v);
}

// Fused qkv GEMM (planar out) + (layer 1 only) proj/lin weight transposes.
// qkv blocks [0,1008): pg = bid%21 (64-pixel group), rg = bid/21 (4 rows of 192).
// x tile in LDS [64][65]; wave = one row x 64 pixels; coalesced planar writes.
// WITH_T blocks [1008,1056): transpose proj_w1/proj_w2/lin_w (64x64 each).
template <bool WITH_T>
__global__ __launch_bounds__(256) void qkv_fused(
    const float* __restrict__ xin, const float* __restrict__ w,
    const float* __restrict__ b, float* __restrict__ planes,
    const float* __restrict__ pw1, const float* __restrict__ pw2,
    const float* __restrict__ lw, float* __restrict__ wT) {
  const int bid = blockIdx.x;
  const int tid = threadIdx.x;
  if (WITH_T && bid >= 1008) {
    const int t = bid - 1008;  // 0..47, 16 blocks per 64x64 matrix
    const int m = t >> 4;
    const int idx = (t & 15) * 256 + tid;
    const float* src = m == 0 ? pw1 : (m == 1 ? pw2 : lw);
    wT[m * 4096 + (idx & 63) * 64 + (idx >> 6)] = src[idx];
    return;
  }
  __shared__ float xs[64][65];
  __shared__ float ws4[4][64];
  const int pg = bid % 21, rg = bid / 21;
  const int wv = tid >> 6, lane = tid & 63;
  const int n0 = pg * 64;
  const int base = n0 * 64;
  const int maxf = 82944 - base;
  const float* xb = xin + base;
#pragma unroll
  for (int t4 = 0; t4 < 4; ++t4) {
    const int fi = (tid + t4 * 256) * 4;
    float4 v = make_float4(0.f, 0.f, 0.f, 0.f);
    if (fi < maxf) v = *(const float4*)(xb + fi);
    const int p = fi >> 6, c = fi & 63;
    xs[p][c] = v.x; xs[p][c + 1] = v.y; xs[p][c + 2] = v.z; xs[p][c + 3] = v.w;
  }
  ws4[tid >> 6][tid & 63] = w[rg * 256 + tid];
  __syncthreads();
  const int r = rg * 4 + wv;
  float acc = b[r];
#pragma unroll
  for (int cc = 0; cc < 64; ++cc) acc += xs[lane][cc] * ws4[wv][cc];
  const int n = n0 + lane;
  if (n < 1296) planes[r * 1296 + n] = acc;
}

// NAT partials, float4 full-row scan.
// grid = 3240: bid -> tile = bid/10, rem = bid%10, s = rem>>1 (5 row-splits of 7),
// pr = rem&1 (query row). Wave = head; 2 queries (iq, j0) and (iq, j0+1).
// Lane = (rr = lane/9 in 0..6, cg = lane%9): key row riq + s*7 + rr,
// key cols 4*cg..4*cg+3 (full 0..35 scan; per-query window masks).
// Record per (bid, head): 36 floats [qq*17+d]=acc, [qq*17+16]=den.
__global__ __launch_bounds__(256, 2) void nat_attn_part(
    const float* __restrict__ planes, const float* __restrict__ rpb,
    float* __restrict__ part) {
  __shared__ float lpart[4][16][35];  // [head][group][2q*17] stride 35 (odd)
  __shared__ float qlds[4][2][16];    // [head][q][d], wave-private

  const int tid = threadIdx.x;
  const int h = tid >> 6;
  const int lane = tid & 63;
  const int bid = blockIdx.x;
  const int tile = bid / 10;
  const int rem = bid - tile * 10;
  const int s = rem >> 1;
  const int pr = rem & 1;
  const int i0 = (tile / 18) * 2;
  const int j0 = (tile % 18) * 2;

  const int iq = i0 + pr;
  const int riq = iclampi(iq - 15, 0, 5);
  const int jqa = j0, jqb = j0 + 1;
  const int cja = iclampi(jqa - 15, 0, 5);
  const int cjb = iclampi(jqb - 15, 0, 5);

  const float* Qp = planes + (size_t)(h * 16) * 1296;
  const float4* Kp4 = (const float4*)(planes + (size_t)(64 + h * 16) * 1296);
  const float4* Vp4 = (const float4*)(planes + (size_t)(128 + h * 16) * 1296);

  // stage this wave's 2 queries (pre-scaled) into wave-private LDS
  if (lane < 32) {
    const int qq = lane >> 4, dd = lane & 15;
    const int nq = iq * 36 + (qq ? jqb : jqa);
    qlds[h][qq][dd] = Qp[dd * 1296 + nq] * 0.25f;
  }

  const int rr = lane / 9;       // 0..7 (7 inactive)
  const int cg = lane - rr * 9;  // 0..8
  const int krr = s * 7 + rr;
  const int rA = riq + krr;
  const bool act = (krr <= 30) && (rr < 7);
  const int rL = rA > 35 ? 35 : rA;
  const int rc9 = rL * 9 + cg;
  const int br = iclampi(rA - iq + 30, 0, 60);
  const float* rpbh = rpb + h * 3721 + br * 61;

  // K pass: dot[qq][j] over 16 d
  float dta[4] = {0.f, 0.f, 0.f, 0.f};
  float dtb[4] = {0.f, 0.f, 0.f, 0.f};
#pragma unroll
  for (int d = 0; d < 16; ++d) {
    const float4 k4 = Kp4[d * 324 + rc9];
    const float qa = qlds[h][0][d], qb = qlds[h][1][d];
    dta[0] += qa * k4.x; dta[1] += qa * k4.y; dta[2] += qa * k4.z; dta[3] += qa * k4.w;
    dtb[0] += qb * k4.x; dtb[1] += qb * k4.y; dtb[2] += qb * k4.z; dtb[3] += qb * k4.w;
  }

  // softmax numerator weights
  float pa[4], pb_[4];
  float dena = 0.f, denb = 0.f;
#pragma unroll
  for (int j = 0; j < 4; ++j) {
    const int col = cg * 4 + j;
    const bool ina = act && (col >= cja) && (col <= cja + 30);
    const bool inb = act && (col >= cjb) && (col <= cjb + 30);
    const int bca = iclampi(col - jqa + 30, 0, 60);
    const int bcb = iclampi(col - jqb + 30, 0, 60);
    const float la = fminf(dta[j] + rpbh[bca], 25.f);  // overflow insurance
    const float lb = fminf(dtb[j] + rpbh[bcb], 25.f);
    pa[j] = ina ? __expf(la) : 0.f;
    pb_[j] = inb ? __expf(lb) : 0.f;
    dena += pa[j];
    denb += pb_[j];
  }

  // V pass: acc[qq][d] = sum_j p[qq][j] * V[d][key j]
  float acca[16], accb[16];
#pragma unroll
  for (int d = 0; d < 16; ++d) {
    const float4 v4 = Vp4[d * 324 + rc9];
    acca[d] = pa[0] * v4.x + pa[1] * v4.y + pa[2] * v4.z + pa[3] * v4.w;
    accb[d] = pb_[0] * v4.x + pb_[1] * v4.y + pb_[2] * v4.z + pb_[3] * v4.w;
  }

  // 2-step butterfly -> 16 groups of 4 lanes
#pragma unroll
  for (int d = 0; d < 16; ++d) {
    acca[d] += __shfl_xor(acca[d], 1);
    acca[d] += __shfl_xor(acca[d], 2);
    accb[d] += __shfl_xor(accb[d], 1);
    accb[d] += __shfl_xor(accb[d], 2);
  }
  dena += __shfl_xor(dena, 1);
  dena += __shfl_xor(dena, 2);
  denb += __shfl_xor(denb, 1);
  denb += __shfl_xor(denb, 2);

  if ((lane & 3) == 0) {
    const int row = lane >> 2;
#pragma unroll
    for (int d = 0; d < 16; ++d) {
      lpart[h][row][d] = acca[d];
      lpart[h][row][17 + d] = accb[d];
    }
    lpart[h][row][16] = dena;
    lpart[h][row][33] = denb;
  }
  // wave-private LDS slab: same wave writes+reads, no __syncthreads needed.

  float* wsout = part + ((size_t)bid * 4 + h) * 36;
  if (lane < 34) {
    float t0 = 0.f;
#pragma unroll
    for (int l = 0; l < 16; ++l) t0 += lpart[h][l][lane];
    wsout[lane] = t0;
  }
}

// Combine partials -> normalize -> projection (transposed weights, coalesced).
// FINAL adds dwconv residual + final linear. grid = 324, block = 256 (wave=query).
// Record: part[tile*1440 + sp*288 + pr*144 + hh*36 + qq*17 + {dd|16}], sp<5.
template <bool FINAL>
__global__ __launch_bounds__(256) void nat_combine(
    const float* __restrict__ part, const float* __restrict__ pwT,
    const float* __restrict__ pb, const float* __restrict__ x,
    const float* __restrict__ dww, const float* __restrict__ dwb,
    const float* __restrict__ linT, const float* __restrict__ lb,
    float* __restrict__ out) {
  __shared__ float att[4][64];
  __shared__ float y_lds[4][64];
  const int tid = threadIdx.x;
  const int q = tid >> 6, lane = tid & 63;
  const int tile = blockIdx.x;
  const int i0 = (tile / 18) * 2, j0 = (tile % 18) * 2;
  const int pr = q >> 1, qq = q & 1;
  const int iq = i0 + pr, jq = j0 + qq;
  const int n = iq * 36 + jq;

  const int hh = lane >> 4, dd = lane & 15;
  const float* pbase = part + (size_t)tile * 1440 + pr * 144 + hh * 36 + qq * 17;
  float num = 0.f, den = 0.f;
#pragma unroll
  for (int sp = 0; sp < 5; ++sp) {
    num += pbase[sp * 288 + dd];
    den += pbase[sp * 288 + 16];
  }
  att[q][lane] = num / den;
  __syncthreads();

  float a = pb[lane];
#pragma unroll
  for (int cc = 0; cc < 64; ++cc) a += att[q][cc] * pwT[cc * 64 + lane];

  if (!FINAL) {
    out[n * 64 + lane] = a;
  } else {
    float y = a + dwb[lane];
#pragma unroll
    for (int di = -1; di <= 1; ++di) {
#pragma unroll
      for (int dj = -1; dj <= 1; ++dj) {
        const int ii = iq + di, jj = jq + dj;
        if (ii >= 0 && ii < 36 && jj >= 0 && jj < 36)
          y += x[(ii * 36 + jj) * 64 + lane] * dww[lane * 9 + (di + 1) * 3 + (dj + 1)];
      }
    }
    y_lds[q][lane] = y;
    __syncthreads();
    float o = lb[lane];
#pragma unroll
    for (int cc = 0; cc < 64; ++cc) o += y_lds[q][cc] * linT[cc * 64 + lane];
    out[n * 64 + lane] = o;
  }
}

}  // namespace

extern "C" void kernel_launch(void* const* d_in, const int* in_sizes, int n_in,
                              void* d_out, int out_size, void* d_ws, size_t ws_size,
                              hipStream_t stream) {
  const float* x       = (const float*)d_in[0];
  const float* qkv_w1  = (const float*)d_in[3];
  const float* qkv_b1  = (const float*)d_in[4];
  const float* rpb1    = (const float*)d_in[5];
  const float* proj_w1 = (const float*)d_in[6];
  const float* proj_b1 = (const float*)d_in[7];
  const float* qkv_w2  = (const float*)d_in[8];
  const float* qkv_b2  = (const float*)d_in[9];
  const float* rpb2    = (const float*)d_in[10];
  const float* proj_w2 = (const float*)d_in[11];
  const float* proj_b2 = (const float*)d_in[12];
  const float* dw_w    = (const float*)d_in[13];
  const float* dw_b    = (const float*)d_in[14];
  const float* lin_w   = (const float*)d_in[15];
  const float* lin_b   = (const float*)d_in[16];
  float* out = (float*)d_out;

  float* ws = (float*)d_ws;
  float* planes = ws;              // 192*1296  = 248832 floats
  float* natA   = ws + 248832;     // 1296*64   =  82944 floats
  float* partb  = natA + 82944;    // 3240*4*36 = 466560 floats
  float* wT     = partb + 466560;  // 3*4096    =  12288 floats
  float* pwT1 = wT;
  float* pwT2 = wT + 4096;
  float* linT = wT + 8192;

  // layer 1 (qkv + weight transposes fused into one launch)
  qkv_fused<true><<<1056, 256, 0, stream>>>(x, qkv_w1, qkv_b1, planes,
                                            proj_w1, proj_w2, lin_w, wT);
  nat_attn_part<<<3240, 256, 0, stream>>>(planes, rpb1, partb);
  nat_combine<false><<<324, 256, 0, stream>>>(partb, pwT1, proj_b1, nullptr,
                                              nullptr, nullptr, nullptr, nullptr,
                                              natA);
  // layer 2
  qkv_fused<false><<<1008, 256, 0, stream>>>(natA, qkv_w2, qkv_b2, planes,
                                             nullptr, nullptr, nullptr, nullptr);
  nat_attn_part<<<3240, 256, 0, stream>>>(planes, rpb2, partb);
  // layer-2 combine + dwconv residual + final linear
  nat_combine<true><<<324, 256, 0, stream>>>(partb, pwT2, proj_b2, x,
                                             dw_w, dw_b, linT, lin_b, out);
}